// Round 2
// baseline (441.006 us; speedup 1.0000x reference)
//
#include <hip/hip_runtime.h>

#define VOCAB 1024
#define CTX 8
#define DDIM 8192      // VOCAB * CTX
#define BATCH 1024
#define RDIM 16        // W-rows (output d's) per block

// ---------------------------------------------------------------------------
// Fused gather kernel. Grid = DDIM/RDIM = 512 blocks x 1024 threads.
//   block b owns d in [b*16, b*16+16); thread tid owns batch row i = tid.
//   For each of the 16 W-rows: stream the 32 KB row into LDS (double-
//   buffered, global_load_lds width=16, counted vmcnt so loads stay in
//   flight across raw s_barriers), then each thread does 8 LDS gathers
//   (offsets precomputed once) and accumulates acc[d_local].
//   Epilogue: out[i, d0:d0+16] = acc + b  -> one full 64B line per thread.
// Traffic: W 256 MB coalesced read (once), out 32 MB full-line writes.
// Occupancy: LDS 64 KB/block -> 2 blocks/CU = 32 waves/CU.
// ---------------------------------------------------------------------------
__global__ __launch_bounds__(1024, 8) void fused_gather(
    const int* __restrict__ x, const float* __restrict__ W,
    const float* __restrict__ b, float* __restrict__ out) {
    __shared__ __align__(16) float lds[2][DDIM];   // 2 x 32 KB
    const int tid = threadIdx.x;
    const int d0  = blockIdx.x * RDIM;

    // --- issue first row's staging immediately (hide latency under setup) ---
    // Each thread moves 2 x 16 B: lds[buf][tid*4] and lds[buf][4096+tid*4].
    // Lane l of each wave -> wave-uniform base + l*16: layout requirement met.
#define STAGE(BUF, DD)                                                         \
    {                                                                          \
        const float* _src = W + (size_t)(d0 + (DD)) * DDIM + tid * 4;          \
        __builtin_amdgcn_global_load_lds(                                      \
            (const __attribute__((address_space(1))) void*)(_src),             \
            (__attribute__((address_space(3))) void*)(&lds[(BUF)][tid * 4]),   \
            16, 0, 0);                                                         \
        __builtin_amdgcn_global_load_lds(                                      \
            (const __attribute__((address_space(1))) void*)(_src + 4096),      \
            (__attribute__((address_space(3))) void*)(&lds[(BUF)][4096 + tid * 4]), \
            16, 0, 0);                                                         \
    }

    STAGE(0, 0)

    // --- per-thread gather offsets (element index within an 8192-float row) ---
    const int4 xa = *reinterpret_cast<const int4*>(x + tid * CTX);
    const int4 xb = *reinterpret_cast<const int4*>(x + tid * CTX + 4);
    const int o0 = xa.x;
    const int o1 = 1 * VOCAB + xa.y;
    const int o2 = 2 * VOCAB + xa.z;
    const int o3 = 3 * VOCAB + xa.w;
    const int o4 = 4 * VOCAB + xb.x;
    const int o5 = 5 * VOCAB + xb.y;
    const int o6 = 6 * VOCAB + xb.z;
    const int o7 = 7 * VOCAB + xb.w;

    float acc[RDIM];

#pragma unroll
    for (int dl = 0; dl < RDIM; ++dl) {
        if (dl < RDIM - 1) {
            STAGE((dl + 1) & 1, dl + 1)                  // prefetch next row
            asm volatile("s_waitcnt vmcnt(2)" ::: "memory");  // cur row landed
        } else {
            asm volatile("s_waitcnt vmcnt(0)" ::: "memory");
        }
        __builtin_amdgcn_s_barrier();                    // cur visible to all

        const float* buf = &lds[dl & 1][0];
        const float v0 = buf[o0];
        const float v1 = buf[o1];
        const float v2 = buf[o2];
        const float v3 = buf[o3];
        const float v4 = buf[o4];
        const float v5 = buf[o5];
        const float v6 = buf[o6];
        const float v7 = buf[o7];
        acc[dl] = ((v0 + v1) + (v2 + v3)) + ((v4 + v5) + (v6 + v7));

        if (dl < RDIM - 1)
            __builtin_amdgcn_s_barrier();                // done reading cur
    }
#undef STAGE

    // --- epilogue: one full 64 B line per thread ---
    const float4 bv0 = *reinterpret_cast<const float4*>(b + d0);
    const float4 bv1 = *reinterpret_cast<const float4*>(b + d0 + 4);
    const float4 bv2 = *reinterpret_cast<const float4*>(b + d0 + 8);
    const float4 bv3 = *reinterpret_cast<const float4*>(b + d0 + 12);
    float* orow = out + (size_t)tid * DDIM + d0;
    float4 r;
    r.x = acc[0] + bv0.x;  r.y = acc[1] + bv0.y;
    r.z = acc[2] + bv0.z;  r.w = acc[3] + bv0.w;
    reinterpret_cast<float4*>(orow)[0] = r;
    r.x = acc[4] + bv1.x;  r.y = acc[5] + bv1.y;
    r.z = acc[6] + bv1.z;  r.w = acc[7] + bv1.w;
    reinterpret_cast<float4*>(orow)[1] = r;
    r.x = acc[8] + bv2.x;  r.y = acc[9] + bv2.y;
    r.z = acc[10] + bv2.z; r.w = acc[11] + bv2.w;
    reinterpret_cast<float4*>(orow)[2] = r;
    r.x = acc[12] + bv3.x; r.y = acc[13] + bv3.y;
    r.z = acc[14] + bv3.z; r.w = acc[15] + bv3.w;
    reinterpret_cast<float4*>(orow)[3] = r;
}

extern "C" void kernel_launch(void* const* d_in, const int* in_sizes, int n_in,
                              void* d_out, int out_size, void* d_ws, size_t ws_size,
                              hipStream_t stream) {
    const int*   x = (const int*)d_in[0];
    const float* W = (const float*)d_in[1];
    const float* b = (const float*)d_in[2];
    float*     out = (float*)d_out;

    hipLaunchKernelGGL(fused_gather, dim3(DDIM / RDIM), dim3(1024), 0, stream,
                       x, W, b, out);
}

// Round 4
// 435.220 us; speedup vs baseline: 1.0133x; 1.0133x over previous
//
#include <hip/hip_runtime.h>

#define VOCAB 1024
#define CTX 8
#define DDIM 8192      // VOCAB * CTX
#define BATCH 1024
#define RDIM 16        // W-rows (output d's) per block
#define TSTR 17        // transpose LDS row stride in floats (odd -> conflict-free)
#define ARENA_FLOATS (BATCH * TSTR)   // 17408 floats = 69632 B  (>= 2*DDIM staging)

// ---------------------------------------------------------------------------
// Fused gather kernel. Grid = DDIM/RDIM = 512 blocks x 1024 threads.
//   Gather loop (unchanged from round 2): double-buffered global_load_lds
//   staging of 16 W-rows with counted vmcnt + raw barriers; thread tid owns
//   batch row tid, 8 precomputed LDS gather offsets, acc[16] in registers.
//   Epilogue: acc+bias -> padded LDS transpose tr[1024][17], then
//   stores arranged so each 4-lane group writes one full 64 B sector of an
//   output row (16 full sectors/instr instead of 64 scattered 16 B chunks).
//   XCD swizzle: adjacent d-blocks share 128 B output lines -> map them
//   to the same XCD L2 so half-lines merge before writeback.
// LDS 69632 B -> 2 blocks/CU = 32 waves/CU.
// ---------------------------------------------------------------------------
__global__ __launch_bounds__(1024, 8) void fused_gather(
    const int* __restrict__ x, const float* __restrict__ W,
    const float* __restrict__ b, float* __restrict__ out) {
    __shared__ __align__(16) float arena[ARENA_FLOATS];
    float* lds0 = arena;           // staging buffer 0 (32 KB)
    float* lds1 = arena + DDIM;    // staging buffer 1 (32 KB)
    float* tr   = arena;           // transpose area (reused after the loop)

    const int tid = threadIdx.x;
    // Bijective XCD swizzle (512 blocks, 8 XCDs, 64 blocks/XCD): consecutive
    // d-blocks end up on the same XCD.
    const int db = ((blockIdx.x & 7) << 6) + (blockIdx.x >> 3);
    const int d0 = db * RDIM;

#define STAGE(DST, DD)                                                         \
    {                                                                          \
        const float* _src = W + (size_t)(d0 + (DD)) * DDIM + tid * 4;          \
        __builtin_amdgcn_global_load_lds(                                      \
            (const __attribute__((address_space(1))) void*)(_src),             \
            (__attribute__((address_space(3))) void*)((DST) + tid * 4),        \
            16, 0, 0);                                                         \
        __builtin_amdgcn_global_load_lds(                                      \
            (const __attribute__((address_space(1))) void*)(_src + 4096),      \
            (__attribute__((address_space(3))) void*)((DST) + 4096 + tid * 4), \
            16, 0, 0);                                                         \
    }

    // x loads first (oldest vmcnt entries -> compiler waits for them without
    // draining the staging loads), then kick off row 0.
    const int4 xa = *reinterpret_cast<const int4*>(x + tid * CTX);
    const int4 xb = *reinterpret_cast<const int4*>(x + tid * CTX + 4);
    STAGE(lds0, 0)

    const int o0 = xa.x;
    const int o1 = 1 * VOCAB + xa.y;
    const int o2 = 2 * VOCAB + xa.z;
    const int o3 = 3 * VOCAB + xa.w;
    const int o4 = 4 * VOCAB + xb.x;
    const int o5 = 5 * VOCAB + xb.y;
    const int o6 = 6 * VOCAB + xb.z;
    const int o7 = 7 * VOCAB + xb.w;

    float acc[RDIM];

#pragma unroll
    for (int dl = 0; dl < RDIM; ++dl) {
        const float* buf = (dl & 1) ? lds1 : lds0;
        if (dl < RDIM - 1) {
            STAGE((dl & 1) ? lds0 : lds1, dl + 1)            // prefetch next
            asm volatile("s_waitcnt vmcnt(2)" ::: "memory"); // cur row landed
        } else {
            asm volatile("s_waitcnt vmcnt(0)" ::: "memory");
        }
        __builtin_amdgcn_s_barrier();                        // cur visible

        const float v0 = buf[o0];
        const float v1 = buf[o1];
        const float v2 = buf[o2];
        const float v3 = buf[o3];
        const float v4 = buf[o4];
        const float v5 = buf[o5];
        const float v6 = buf[o6];
        const float v7 = buf[o7];
        acc[dl] = ((v0 + v1) + (v2 + v3)) + ((v4 + v5) + (v6 + v7));

        asm volatile("s_waitcnt lgkmcnt(0)" ::: "memory");   // reads done
        __builtin_amdgcn_s_barrier();                        // safe to reuse
    }
#undef STAGE

    // --- epilogue: transpose through LDS, full-sector stores ---
    float bv[RDIM];
#pragma unroll
    for (int k = 0; k < RDIM; ++k) bv[k] = b[d0 + k];        // uniform s_loads

    // tr[row=tid][k], stride 17: per instruction banks = 17*l mod 32, all
    // distinct over 32 lanes; lane l / l+32 alias = free 2-way.
#pragma unroll
    for (int k = 0; k < RDIM; ++k) tr[tid * TSTR + k] = acc[k] + bv[k];
    asm volatile("s_waitcnt lgkmcnt(0)" ::: "memory");
    __builtin_amdgcn_s_barrier();

    const int lane = tid & 63;
    const int wid  = tid >> 6;
    const int colg = (lane & 3) << 2;   // 0,4,8,12
    const int rsub = lane >> 2;         // 0..15
#pragma unroll
    for (int c = 0; c < 4; ++c) {
        const int row = (wid << 6) + (c << 4) + rsub;        // batch row
        const float* s = tr + row * TSTR + colg;
        float4 v;
        v.x = s[0]; v.y = s[1]; v.z = s[2]; v.w = s[3];
        // lanes 4k..4k+3 cover one contiguous 64 B sector of row's output
        *reinterpret_cast<float4*>(out + (size_t)row * DDIM + d0 + colg) = v;
    }
}

extern "C" void kernel_launch(void* const* d_in, const int* in_sizes, int n_in,
                              void* d_out, int out_size, void* d_ws, size_t ws_size,
                              hipStream_t stream) {
    const int*   x = (const int*)d_in[0];
    const float* W = (const float*)d_in[1];
    const float* b = (const float*)d_in[2];
    float*     out = (float*)d_out;

    hipLaunchKernelGGL(fused_gather, dim3(DDIM / RDIM), dim3(1024), 0, stream,
                       x, W, b, out);
}